// Round 7
// baseline (442.759 us; speedup 1.0000x reference)
//
#include <hip/hip_runtime.h>
#include <hip/hip_bf16.h>
#include <math.h>

// Problem constants
#define BATCH 8192
#define HD    256
#define NPTS  51              // nb_steps=50 -> 51 quadrature points
#define MTOT  (BATCH*NPTS)    // 417792 = 256 * 1632

typedef __bf16 bf16x8 __attribute__((ext_vector_type(8)));
typedef float  f32x4  __attribute__((ext_vector_type(4)));

// ---- workspace layout (bytes) ----
#define OFF_IW2P  0            // 65536 ushort: iw2 bf16, CHUNK-MAJOR per col-half:
                               //   iw2p[h*32768 + c*1024 + n*8 + j] = bf16(iw2[(h*128+n)*256 + c*8 + j])
#define OFF_W1X   131072       // 256 f32 (iw1[:,0])
#define OFF_CC    132096       // 64 f32
#define OFF_STEPS 132352       // 64 f32
#define OFF_OFFS  132608       // 8192 f32
#define OFF_SCAL  165376       // 8192 f32
#define OFF_G1    198144       // 8192*256 f32 (h-part of layer1 + ib1, NO relu)
#define OFF_FV0   8586752      // 417792 f32 partial dot, col-half 0
#define OFF_FV1   10257920     // 417792 f32 partial dot, col-half 1  (ends 11929088)

__device__ __forceinline__ unsigned short f2bf(float f) {
    union { float f; unsigned u; } v; v.f = f;
    unsigned r = v.u + 0x7FFFu + ((v.u >> 16) & 1u);   // RTNE
    return (unsigned short)(r >> 16);
}

__device__ __forceinline__ unsigned pk2bf(float lo, float hi) {
    __hip_bfloat162 t = __float22bfloat162_rn(float2{lo, hi});
    union { __hip_bfloat162 b; unsigned u; } v; v.b = t;
    return v.u;
}

// ---------------- K1: fused prep + second network ----------------
// blocks 0..255  : iw2 fp32 -> chunk-major bf16 iw2p
// block 256      : w1xs (iw1 col 0), CC weights + nodes (f32, integer mod-100 reduction)
// blocks 257..768: per-16-batch fused: g1(write) + a1n(LDS bf16) + nnet MFMA
//                  (B converted on-the-fly from f32 nw2) -> offs/scal.
__global__ void k1_fused(const float* __restrict__ iw2, const float* __restrict__ nw1,
                         const float* __restrict__ iw1, const float* __restrict__ ib1,
                         const float* __restrict__ nb1, const float* __restrict__ h,
                         const float* __restrict__ nw2, const float* __restrict__ nb2,
                         const float* __restrict__ nw3, const float* __restrict__ nb3,
                         unsigned short* iw2p, float* w1xs, float* cc, float* steps,
                         float* __restrict__ g1, float* __restrict__ offs,
                         float* __restrict__ scal) {
    int blk = blockIdx.x, tid = threadIdx.x;
    if (blk < 256) {
        int t = blk * 256 + tid;           // t = n*256 + k
        int n = t >> 8, k = t & 255;
        int half = n >> 7, nl = n & 127, c = k >> 3, j = k & 7;
        iw2p[half * 32768 + c * 1024 + nl * 8 + j] = f2bf(iw2[t]);
    } else if (blk == 256) {
        w1xs[tid] = iw1[tid * 16];   // column 0 of iw1
        const float PI_F = 3.14159265358979323846f;
        if (tid <= 50) {
            int j = tid;
            float s = 0.f;
            for (int i = 0; i <= 50; i += 2) {          // odd i have W=0
                float w = (i == 0) ? 1.f : 2.f / (1.f - (float)(i * i));
                float l;
                if (j == 0 || j == 50) l = 0.5f;
                else { int r = (i * j) % 100; l = __cosf((float)r * (PI_F / 50.f)); }
                s += l * w;
            }
            cc[j]    = s * (2.f / 50.f);
            steps[j] = __cosf((float)j * (PI_F / 50.f));
        }
    } else {
        __shared__ float hs[16][15];
        __shared__ unsigned short a1s[16][264];   // bf16 relu(h@nw1.T+nb1), padded stride
        __shared__ float Pp[4 * 2 * 16];
        int b0 = (blk - 257) * 16, n = tid;
        if (tid < 240) { int bb = tid / 15, j = tid % 15; hs[bb][j] = h[(b0 + bb) * 15 + j]; }
        __syncthreads();
        float ir[16], nr[15];
        const float4* ip = (const float4*)(iw1 + n * 16);
        ((float4*)ir)[0] = ip[0]; ((float4*)ir)[1] = ip[1];
        ((float4*)ir)[2] = ip[2]; ((float4*)ir)[3] = ip[3];
        #pragma unroll
        for (int j = 0; j < 15; ++j) nr[j] = nw1[n * 15 + j];
        float bi = ib1[n], bn = nb1[n];
        #pragma unroll
        for (int bb = 0; bb < 16; ++bb) {
            float g = bi, a = bn;
            #pragma unroll
            for (int j = 0; j < 15; ++j) { float hv = hs[bb][j]; g += hv * ir[j + 1]; a += hv * nr[j]; }
            g1[(b0 + bb) * 256 + n] = g;
            a1s[bb][n] = f2bf(fmaxf(a, 0.f));
        }
        __syncthreads();

        // ---- nnet layer2 MFMA: A = a1s (16 batches x 256k), wave w owns 64 n ----
        int lane = tid & 63, w = tid >> 6, l16 = lane & 15, quad = lane >> 4;
        f32x4 acc[4];
        #pragma unroll
        for (int nt = 0; nt < 4; ++nt) acc[nt] = (f32x4){0.f, 0.f, 0.f, 0.f};
        #pragma unroll
        for (int ks = 0; ks < 8; ++ks) {
            bf16x8 af = *(const bf16x8*)&a1s[l16][ks * 32 + quad * 8];
            #pragma unroll
            for (int nt = 0; nt < 4; ++nt) {
                const float* np = nw2 + (w * 64 + nt * 16 + l16) * 256 + ks * 32 + quad * 8;
                float4 f0 = ((const float4*)np)[0];
                float4 f1 = ((const float4*)np)[1];
                union { uint4 u; bf16x8 v; } bf;
                bf.u.x = pk2bf(f0.x, f0.y); bf.u.y = pk2bf(f0.z, f0.w);
                bf.u.z = pk2bf(f1.x, f1.y); bf.u.w = pk2bf(f1.z, f1.w);
                acc[nt] = __builtin_amdgcn_mfma_f32_16x16x32_bf16(af, bf.v, acc[nt], 0, 0, 0);
            }
        }
        float p0[4], p1[4];
        #pragma unroll
        for (int i = 0; i < 4; ++i) { p0[i] = 0.f; p1[i] = 0.f; }
        #pragma unroll
        for (int nt = 0; nt < 4; ++nt) {
            int nn = w * 64 + nt * 16 + l16;
            float bias = nb2[nn], wa = nw3[nn], wb = nw3[256 + nn];
            #pragma unroll
            for (int i = 0; i < 4; ++i) {
                float v = acc[nt][i] + bias;
                v = v > 0.f ? v : 0.f;
                p0[i] += v * wa;
                p1[i] += v * wb;
            }
        }
        #pragma unroll
        for (int mask = 1; mask < 16; mask <<= 1)
            #pragma unroll
            for (int i = 0; i < 4; ++i) {
                p0[i] += __shfl_xor(p0[i], mask, 64);
                p1[i] += __shfl_xor(p1[i], mask, 64);
            }
        if (l16 == 0) {
            #pragma unroll
            for (int i = 0; i < 4; ++i) {
                int r = quad * 4 + i;                  // 0..15
                Pp[w * 32 + r]      = p0[i];
                Pp[w * 32 + 16 + r] = p1[i];
            }
        }
        __syncthreads();
        if (tid < 16) {
            float s0 = Pp[tid]      + Pp[32 + tid] + Pp[64 + tid] + Pp[96 + tid]  + nb3[0];
            float s1 = Pp[16 + tid] + Pp[48 + tid] + Pp[80 + tid] + Pp[112 + tid] + nb3[1];
            offs[b0 + tid] = s0;
            scal[b0 + tid] = __expf(s1);
        }
    }
}

// ---------------- k2: main integrand GEMM ----------------
// Block = 256 rows x 128 cols (col-half hf), K=256. 4 waves, wave w owns rows
// [w*64, w*64+64) x all 128 cols: acc[4][8]. B col-half streamed as four 16KB
// k-chunks (64 k each), double-buffered via global_load_lds (prefetch issued
// right after each barrier). A fragments computed in registers from g1 + xs*w1x.
// LDS = 32KB; target 3 blocks/CU.
__launch_bounds__(256, 3)
__global__ void k2_main(const float* __restrict__ x, const float* __restrict__ g1,
                        const float* __restrict__ w1xs, const unsigned short* __restrict__ iw2p,
                        const float* __restrict__ ib2, const float* __restrict__ iw3,
                        const float* __restrict__ steps,
                        float* __restrict__ fv0, float* __restrict__ fv1) {
    __shared__ __align__(16) unsigned char smem[32768];   // 2 x 16KB B chunk buffers
    float* Pp = (float*)smem;                             // aliased for epilogue: [256][20] f32

    int tid = threadIdx.x;
    int bid = blockIdx.x;
    int hf  = bid & 1;
    int m0  = (bid >> 1) * 256;
    int lane = tid & 63, w = tid >> 6;
    int l16 = lane & 15, quad = lane >> 4;

    const unsigned char* bsrc = (const unsigned char*)iw2p + hf * 65536 + tid * 16;

    // DMA chunk 0 into buf 0: 16KB = 256 thr x 16B x 4
    #pragma unroll
    for (int it = 0; it < 4; ++it)
        __builtin_amdgcn_global_load_lds(
            (const __attribute__((address_space(1))) unsigned int*)(bsrc + it * 4096),
            (__attribute__((address_space(3))) unsigned int*)(smem + tid * 16 + it * 4096),
            16, 0, 0);

    // per-m-group row constants (batch base, x-scale) — overlaps with DMA
    float xs_[4]; int gb_[4];
    #pragma unroll
    for (int mt = 0; mt < 4; ++mt) {
        int m = m0 + w * 64 + mt * 16 + l16;
        unsigned b = (unsigned)(((unsigned long long)(unsigned)m * 657931ull) >> 25);  // m/51, exact here
        int p = m - (int)b * 51;
        xs_[mt] = x[b] * (steps[p] + 1.f) * 0.5f;
        gb_[mt] = (int)b * 256;
    }

    f32x4 acc[4][8];
    #pragma unroll
    for (int mt = 0; mt < 4; ++mt)
        #pragma unroll
        for (int nt = 0; nt < 8; ++nt)
            acc[mt][nt] = (f32x4){0.f, 0.f, 0.f, 0.f};

    #pragma unroll
    for (int kc = 0; kc < 4; ++kc) {
        __syncthreads();                       // DMA(kc) drained + all waves aligned
        if (kc < 3) {                          // prefetch next chunk into other buf
            const unsigned char* s2 = bsrc + (kc + 1) * 16384;
            unsigned char* d2 = smem + ((kc + 1) & 1) * 16384 + tid * 16;
            #pragma unroll
            for (int it = 0; it < 4; ++it)
                __builtin_amdgcn_global_load_lds(
                    (const __attribute__((address_space(1))) unsigned int*)(s2 + it * 4096),
                    (__attribute__((address_space(3))) unsigned int*)(d2 + it * 4096),
                    16, 0, 0);
        }
        const unsigned short* Bl = (const unsigned short*)(smem + (kc & 1) * 16384);
        #pragma unroll
        for (int s = 0; s < 2; ++s) {
            int ks = kc * 2 + s;               // global 32-wide k-step 0..7
            int ko = ks * 32 + quad * 8;
            int cl = s * 4 + quad;             // chunk-local c 0..7
            bf16x8 bfr[8];
            #pragma unroll
            for (int nt = 0; nt < 8; ++nt)
                bfr[nt] = *(const bf16x8*)(Bl + (cl * 128 + nt * 16 + l16) * 8);
            float4 w0 = ((const float4*)(w1xs + ko))[0];
            float4 w1 = ((const float4*)(w1xs + ko))[1];
            #pragma unroll
            for (int mt = 0; mt < 4; ++mt) {
                const float* gp = g1 + gb_[mt] + ko;
                float4 ga  = ((const float4*)gp)[0];
                float4 gb2 = ((const float4*)gp)[1];
                float xs = xs_[mt];
                float a0 = fmaxf(ga.x  + xs * w0.x, 0.f);
                float a1 = fmaxf(ga.y  + xs * w0.y, 0.f);
                float a2 = fmaxf(ga.z  + xs * w0.z, 0.f);
                float a3 = fmaxf(ga.w  + xs * w0.w, 0.f);
                float a4 = fmaxf(gb2.x + xs * w1.x, 0.f);
                float a5 = fmaxf(gb2.y + xs * w1.y, 0.f);
                float a6 = fmaxf(gb2.z + xs * w1.z, 0.f);
                float a7 = fmaxf(gb2.w + xs * w1.w, 0.f);
                union { uint4 u; bf16x8 v; } af;
                af.u.x = pk2bf(a0, a1); af.u.y = pk2bf(a2, a3);
                af.u.z = pk2bf(a4, a5); af.u.w = pk2bf(a6, a7);
                #pragma unroll
                for (int nt = 0; nt < 8; ++nt)
                    acc[mt][nt] = __builtin_amdgcn_mfma_f32_16x16x32_bf16(af.v, bfr[nt], acc[mt][nt], 0, 0, 0);
            }
        }
    }

    // ---- epilogue: relu(+ib2), dot with iw3 over this block's 128 cols ----
    float pf[4][4];
    #pragma unroll
    for (int mt = 0; mt < 4; ++mt)
        #pragma unroll
        for (int i = 0; i < 4; ++i) pf[mt][i] = 0.f;
    #pragma unroll
    for (int nt = 0; nt < 8; ++nt) {
        int n = hf * 128 + nt * 16 + l16;
        float bias = ib2[n], w3 = iw3[n];
        #pragma unroll
        for (int mt = 0; mt < 4; ++mt)
            #pragma unroll
            for (int i = 0; i < 4; ++i) {
                float v = acc[mt][nt][i] + bias;
                v = v > 0.f ? v : 0.f;
                pf[mt][i] += v * w3;
            }
    }
    __syncthreads();     // all Bl reads done; smem becomes Pp
    #pragma unroll
    for (int mt = 0; mt < 4; ++mt)
        #pragma unroll
        for (int i = 0; i < 4; ++i) {
            int row = w * 64 + mt * 16 + quad * 4 + i;
            Pp[row * 20 + l16] = pf[mt][i];
        }
    __syncthreads();
    {
        const float4* pp = (const float4*)(Pp + tid * 20);
        float4 v0 = pp[0], v1 = pp[1], v2 = pp[2], v3 = pp[3];
        float s = v0.x + v0.y + v0.z + v0.w + v1.x + v1.y + v1.z + v1.w
                + v2.x + v2.y + v2.z + v2.w + v3.x + v3.y + v3.z + v3.w;
        (hf ? fv1 : fv0)[m0 + tid] = s;     // partial (over 128 cols), pre-elu
    }
}

// ---------------- k4: elu + quadrature reduce + combine (wave per batch) ----------------
__global__ void k4_final(const float* __restrict__ x, const float* __restrict__ fv0,
                         const float* __restrict__ fv1, const float* __restrict__ ib3,
                         const float* __restrict__ cc,
                         const float* __restrict__ offs, const float* __restrict__ scal,
                         float* __restrict__ out) {
    int tid = threadIdx.x;
    int wv = tid >> 6, lane = tid & 63;
    int b = blockIdx.x * 4 + wv;
    float v = 0.f;
    if (lane < 51) {
        int m = b * 51 + lane;
        float s = fv0[m] + fv1[m] + ib3[0];
        float f = s > 0.f ? s + 1.f : __expf(s);   // elu(s)+1
        v = f * cc[lane];
    }
    #pragma unroll
    for (int mask = 1; mask < 64; mask <<= 1) v += __shfl_xor(v, mask, 64);
    if (lane == 0)
        out[b] = scal[b] * (0.5f * x[b] * v) + offs[b];
}

extern "C" void kernel_launch(void* const* d_in, const int* in_sizes, int n_in,
                              void* d_out, int out_size, void* d_ws, size_t ws_size,
                              hipStream_t stream) {
    const float* x   = (const float*)d_in[0];
    const float* h   = (const float*)d_in[1];
    const float* iw1 = (const float*)d_in[2];
    const float* ib1 = (const float*)d_in[3];
    const float* iw2 = (const float*)d_in[4];
    const float* ib2 = (const float*)d_in[5];
    const float* iw3 = (const float*)d_in[6];
    const float* ib3 = (const float*)d_in[7];
    const float* nw1 = (const float*)d_in[8];
    const float* nb1 = (const float*)d_in[9];
    const float* nw2 = (const float*)d_in[10];
    const float* nb2 = (const float*)d_in[11];
    const float* nw3 = (const float*)d_in[12];
    const float* nb3 = (const float*)d_in[13];
    float* out = (float*)d_out;

    char* ws = (char*)d_ws;
    unsigned short* iw2p = (unsigned short*)(ws + OFF_IW2P);
    float* w1xs  = (float*)(ws + OFF_W1X);
    float* cc    = (float*)(ws + OFF_CC);
    float* steps = (float*)(ws + OFF_STEPS);
    float* offs  = (float*)(ws + OFF_OFFS);
    float* scal  = (float*)(ws + OFF_SCAL);
    float* g1    = (float*)(ws + OFF_G1);
    float* fv0   = (float*)(ws + OFF_FV0);
    float* fv1   = (float*)(ws + OFF_FV1);

    k1_fused<<<dim3(769), dim3(256), 0, stream>>>(iw2, nw1, iw1, ib1, nb1, h,
                                                  nw2, nb2, nw3, nb3,
                                                  iw2p, w1xs, cc, steps, g1, offs, scal);
    k2_main<<<dim3((MTOT / 256) * 2), dim3(256), 0, stream>>>(x, g1, w1xs, iw2p, ib2, iw3,
                                                              steps, fv0, fv1);
    k4_final<<<dim3(BATCH / 4), dim3(256), 0, stream>>>(x, fv0, fv1, ib3, cc, offs, scal, out);
}

// Round 8
// 168.305 us; speedup vs baseline: 2.6307x; 2.6307x over previous
//
#include <hip/hip_runtime.h>
#include <hip/hip_bf16.h>
#include <math.h>

// Problem constants
#define BATCH 8192
#define HD    256
#define NPTS  51              // nb_steps=50 -> 51 quadrature points
#define MTOT  (BATCH*NPTS)    // 417792 = 128 * 3264

typedef __bf16 bf16x8 __attribute__((ext_vector_type(8)));
typedef float  f32x4  __attribute__((ext_vector_type(4)));

// ---- workspace layout (bytes) ----
#define OFF_IW2P  0            // 65536 ushort: iw2 bf16, CHUNK-MAJOR per col-half:
                               //   iw2p[h*32768 + c*1024 + n*8 + j] = bf16(iw2[(h*128+n)*256 + c*8 + j])
#define OFF_W1X   131072       // 256 f32 (iw1[:,0])
#define OFF_CC    132096       // 64 f32
#define OFF_STEPS 132352       // 64 f32
#define OFF_OFFS  132608       // 8192 f32
#define OFF_SCAL  165376       // 8192 f32
#define OFF_G1    198144       // 8192*256 f32 (h-part of layer1 + ib1, NO relu)
#define OFF_FV0   8586752      // 417792 f32 partial dot, col-half 0
#define OFF_FV1   10257920     // 417792 f32 partial dot, col-half 1  (ends 11929088)

__device__ __forceinline__ unsigned short f2bf(float f) {
    union { float f; unsigned u; } v; v.f = f;
    unsigned r = v.u + 0x7FFFu + ((v.u >> 16) & 1u);   // RTNE
    return (unsigned short)(r >> 16);
}

__device__ __forceinline__ unsigned pk2bf(float lo, float hi) {
    __hip_bfloat162 t = __float22bfloat162_rn(float2{lo, hi});
    union { __hip_bfloat162 b; unsigned u; } v; v.b = t;
    return v.u;
}

// ---------------- K1: fused prep + second network ----------------
__global__ void k1_fused(const float* __restrict__ iw2, const float* __restrict__ nw1,
                         const float* __restrict__ iw1, const float* __restrict__ ib1,
                         const float* __restrict__ nb1, const float* __restrict__ h,
                         const float* __restrict__ nw2, const float* __restrict__ nb2,
                         const float* __restrict__ nw3, const float* __restrict__ nb3,
                         unsigned short* iw2p, float* w1xs, float* cc, float* steps,
                         float* __restrict__ g1, float* __restrict__ offs,
                         float* __restrict__ scal) {
    int blk = blockIdx.x, tid = threadIdx.x;
    if (blk < 256) {
        int t = blk * 256 + tid;           // t = n*256 + k
        int n = t >> 8, k = t & 255;
        int half = n >> 7, nl = n & 127, c = k >> 3, j = k & 7;
        iw2p[half * 32768 + c * 1024 + nl * 8 + j] = f2bf(iw2[t]);
    } else if (blk == 256) {
        w1xs[tid] = iw1[tid * 16];   // column 0 of iw1
        const float PI_F = 3.14159265358979323846f;
        if (tid <= 50) {
            int j = tid;
            float s = 0.f;
            for (int i = 0; i <= 50; i += 2) {          // odd i have W=0
                float w = (i == 0) ? 1.f : 2.f / (1.f - (float)(i * i));
                float l;
                if (j == 0 || j == 50) l = 0.5f;
                else { int r = (i * j) % 100; l = __cosf((float)r * (PI_F / 50.f)); }
                s += l * w;
            }
            cc[j]    = s * (2.f / 50.f);
            steps[j] = __cosf((float)j * (PI_F / 50.f));
        }
    } else {
        __shared__ float hs[16][15];
        __shared__ unsigned short a1s[16][264];   // bf16 relu(h@nw1.T+nb1), padded stride
        __shared__ float Pp[4 * 2 * 16];
        int b0 = (blk - 257) * 16, n = tid;
        if (tid < 240) { int bb = tid / 15, j = tid % 15; hs[bb][j] = h[(b0 + bb) * 15 + j]; }
        __syncthreads();
        float ir[16], nr[15];
        const float4* ip = (const float4*)(iw1 + n * 16);
        ((float4*)ir)[0] = ip[0]; ((float4*)ir)[1] = ip[1];
        ((float4*)ir)[2] = ip[2]; ((float4*)ir)[3] = ip[3];
        #pragma unroll
        for (int j = 0; j < 15; ++j) nr[j] = nw1[n * 15 + j];
        float bi = ib1[n], bn = nb1[n];
        #pragma unroll
        for (int bb = 0; bb < 16; ++bb) {
            float g = bi, a = bn;
            #pragma unroll
            for (int j = 0; j < 15; ++j) { float hv = hs[bb][j]; g += hv * ir[j + 1]; a += hv * nr[j]; }
            g1[(b0 + bb) * 256 + n] = g;
            a1s[bb][n] = f2bf(fmaxf(a, 0.f));
        }
        __syncthreads();

        // ---- nnet layer2 MFMA: A = a1s (16 batches x 256k), wave w owns 64 n ----
        int lane = tid & 63, w = tid >> 6, l16 = lane & 15, quad = lane >> 4;
        f32x4 acc[4];
        #pragma unroll
        for (int nt = 0; nt < 4; ++nt) acc[nt] = (f32x4){0.f, 0.f, 0.f, 0.f};
        #pragma unroll
        for (int ks = 0; ks < 8; ++ks) {
            bf16x8 af = *(const bf16x8*)&a1s[l16][ks * 32 + quad * 8];
            #pragma unroll
            for (int nt = 0; nt < 4; ++nt) {
                const float* np = nw2 + (w * 64 + nt * 16 + l16) * 256 + ks * 32 + quad * 8;
                float4 f0 = ((const float4*)np)[0];
                float4 f1 = ((const float4*)np)[1];
                union { uint4 u; bf16x8 v; } bf;
                bf.u.x = pk2bf(f0.x, f0.y); bf.u.y = pk2bf(f0.z, f0.w);
                bf.u.z = pk2bf(f1.x, f1.y); bf.u.w = pk2bf(f1.z, f1.w);
                acc[nt] = __builtin_amdgcn_mfma_f32_16x16x32_bf16(af, bf.v, acc[nt], 0, 0, 0);
            }
        }
        float p0[4], p1[4];
        #pragma unroll
        for (int i = 0; i < 4; ++i) { p0[i] = 0.f; p1[i] = 0.f; }
        #pragma unroll
        for (int nt = 0; nt < 4; ++nt) {
            int nn = w * 64 + nt * 16 + l16;
            float bias = nb2[nn], wa = nw3[nn], wb = nw3[256 + nn];
            #pragma unroll
            for (int i = 0; i < 4; ++i) {
                float v = acc[nt][i] + bias;
                v = v > 0.f ? v : 0.f;
                p0[i] += v * wa;
                p1[i] += v * wb;
            }
        }
        #pragma unroll
        for (int mask = 1; mask < 16; mask <<= 1)
            #pragma unroll
            for (int i = 0; i < 4; ++i) {
                p0[i] += __shfl_xor(p0[i], mask, 64);
                p1[i] += __shfl_xor(p1[i], mask, 64);
            }
        if (l16 == 0) {
            #pragma unroll
            for (int i = 0; i < 4; ++i) {
                int r = quad * 4 + i;                  // 0..15
                Pp[w * 32 + r]      = p0[i];
                Pp[w * 32 + 16 + r] = p1[i];
            }
        }
        __syncthreads();
        if (tid < 16) {
            float s0 = Pp[tid]      + Pp[32 + tid] + Pp[64 + tid] + Pp[96 + tid]  + nb3[0];
            float s1 = Pp[16 + tid] + Pp[48 + tid] + Pp[80 + tid] + Pp[112 + tid] + nb3[1];
            offs[b0 + tid] = s0;
            scal[b0 + tid] = __expf(s1);
        }
    }
}

// ---------------- k2: main integrand GEMM ----------------
// Block = 128 rows x 128 cols (col-half hf), K=256. 4 waves, wave w owns rows
// [w*32, w*32+32): acc[2][8] = 64 acc regs (the max that avoids spill at 3 blocks/CU
// -- R7 post-mortem: acc[4][8] under launch_bounds(256,3) spilled 1GB to scratch).
// ALL A-side inputs staged in LDS up front: g1 rows (block spans <=4 batches, 4KB)
// and w1x (1KB) DMA'd alongside B chunk 0 -> K-loop touches global memory ZERO times.
// B col-half streamed as four 16KB k-chunks, double-buffered via global_load_lds.
__launch_bounds__(256, 3)
__global__ void k2_main(const float* __restrict__ x, const float* __restrict__ g1,
                        const float* __restrict__ w1xs, const unsigned short* __restrict__ iw2p,
                        const float* __restrict__ ib2, const float* __restrict__ iw3,
                        const float* __restrict__ steps,
                        float* __restrict__ fv0, float* __restrict__ fv1) {
    __shared__ __align__(16) unsigned char smem[37888];   // [0,32K) B dbuf | [32K,36K) g1 | [36K,37K) w1x
    float* Pp = (float*)smem;                             // aliased for epilogue: [128][20] f32

    int tid = threadIdx.x;
    int bid = blockIdx.x;
    int hf  = bid & 1;
    int m0  = (bid >> 1) * 128;
    int lane = tid & 63, w = tid >> 6;
    int l16 = lane & 15, quad = lane >> 4;

    unsigned blo = (unsigned)(((unsigned long long)(unsigned)m0 * 657931ull) >> 25);  // m0/51

    const unsigned char* bsrc = (const unsigned char*)iw2p + hf * 65536 + tid * 16;

    // DMA B chunk 0 into buf 0 (16KB), g1 rows blo..blo+3 (4KB), w1x (1KB)
    #pragma unroll
    for (int it = 0; it < 4; ++it)
        __builtin_amdgcn_global_load_lds(
            (const __attribute__((address_space(1))) unsigned int*)(bsrc + it * 4096),
            (__attribute__((address_space(3))) unsigned int*)(smem + tid * 16 + it * 4096),
            16, 0, 0);
    __builtin_amdgcn_global_load_lds(
        (const __attribute__((address_space(1))) unsigned int*)((const unsigned char*)(g1 + blo * 256) + tid * 16),
        (__attribute__((address_space(3))) unsigned int*)(smem + 32768 + tid * 16),
        16, 0, 0);
    if (w == 0)
        __builtin_amdgcn_global_load_lds(
            (const __attribute__((address_space(1))) unsigned int*)((const unsigned char*)w1xs + lane * 16),
            (__attribute__((address_space(3))) unsigned int*)(smem + 36864 + lane * 16),
            16, 0, 0);

    // per-m-group row constants (batch rel offset, x-scale) — overlaps with DMA
    float xs_[2]; int rel_[2];
    #pragma unroll
    for (int mt = 0; mt < 2; ++mt) {
        int m = m0 + w * 32 + mt * 16 + l16;
        unsigned b = (unsigned)(((unsigned long long)(unsigned)m * 657931ull) >> 25);  // m/51
        int p = m - (int)b * 51;
        xs_[mt] = x[b] * (steps[p] + 1.f) * 0.5f;
        rel_[mt] = (int)(b - blo) * 256;
    }

    f32x4 acc[2][8];
    #pragma unroll
    for (int mt = 0; mt < 2; ++mt)
        #pragma unroll
        for (int nt = 0; nt < 8; ++nt)
            acc[mt][nt] = (f32x4){0.f, 0.f, 0.f, 0.f};

    const float* Ag = (const float*)(smem + 32768);   // [4][256] g1 rows
    const float* Wl = (const float*)(smem + 36864);   // [256] w1x

    #pragma unroll
    for (int kc = 0; kc < 4; ++kc) {
        __syncthreads();                       // DMA(kc) drained + all waves aligned
        if (kc < 3) {                          // prefetch next chunk into other buf
            const unsigned char* s2 = bsrc + (kc + 1) * 16384;
            unsigned char* d2 = smem + ((kc + 1) & 1) * 16384 + tid * 16;
            #pragma unroll
            for (int it = 0; it < 4; ++it)
                __builtin_amdgcn_global_load_lds(
                    (const __attribute__((address_space(1))) unsigned int*)(s2 + it * 4096),
                    (__attribute__((address_space(3))) unsigned int*)(d2 + it * 4096),
                    16, 0, 0);
        }
        const unsigned short* Bl = (const unsigned short*)(smem + (kc & 1) * 16384);
        #pragma unroll
        for (int s = 0; s < 2; ++s) {
            int ks = kc * 2 + s;               // global 32-wide k-step 0..7
            int ko = ks * 32 + quad * 8;
            int cl = s * 4 + quad;             // chunk-local c 0..7
            bf16x8 bfr[8];
            #pragma unroll
            for (int nt = 0; nt < 8; ++nt)
                bfr[nt] = *(const bf16x8*)(Bl + (cl * 128 + nt * 16 + l16) * 8);
            float4 w0 = ((const float4*)(Wl + ko))[0];
            float4 w1 = ((const float4*)(Wl + ko))[1];
            #pragma unroll
            for (int mt = 0; mt < 2; ++mt) {
                const float* gp = Ag + rel_[mt] + ko;
                float4 ga  = ((const float4*)gp)[0];
                float4 gb2 = ((const float4*)gp)[1];
                float xs = xs_[mt];
                float a0 = fmaxf(ga.x  + xs * w0.x, 0.f);
                float a1 = fmaxf(ga.y  + xs * w0.y, 0.f);
                float a2 = fmaxf(ga.z  + xs * w0.z, 0.f);
                float a3 = fmaxf(ga.w  + xs * w0.w, 0.f);
                float a4 = fmaxf(gb2.x + xs * w1.x, 0.f);
                float a5 = fmaxf(gb2.y + xs * w1.y, 0.f);
                float a6 = fmaxf(gb2.z + xs * w1.z, 0.f);
                float a7 = fmaxf(gb2.w + xs * w1.w, 0.f);
                union { uint4 u; bf16x8 v; } af;
                af.u.x = pk2bf(a0, a1); af.u.y = pk2bf(a2, a3);
                af.u.z = pk2bf(a4, a5); af.u.w = pk2bf(a6, a7);
                #pragma unroll
                for (int nt = 0; nt < 8; ++nt)
                    acc[mt][nt] = __builtin_amdgcn_mfma_f32_16x16x32_bf16(af.v, bfr[nt], acc[mt][nt], 0, 0, 0);
            }
        }
    }

    // ---- epilogue: relu(+ib2), dot with iw3 over this block's 128 cols ----
    float pf[2][4];
    #pragma unroll
    for (int mt = 0; mt < 2; ++mt)
        #pragma unroll
        for (int i = 0; i < 4; ++i) pf[mt][i] = 0.f;
    #pragma unroll
    for (int nt = 0; nt < 8; ++nt) {
        int n = hf * 128 + nt * 16 + l16;
        float bias = ib2[n], w3 = iw3[n];
        #pragma unroll
        for (int mt = 0; mt < 2; ++mt)
            #pragma unroll
            for (int i = 0; i < 4; ++i) {
                float v = acc[mt][nt][i] + bias;
                v = v > 0.f ? v : 0.f;
                pf[mt][i] += v * w3;
            }
    }
    __syncthreads();     // all Bl/Ag reads done; smem becomes Pp
    #pragma unroll
    for (int mt = 0; mt < 2; ++mt)
        #pragma unroll
        for (int i = 0; i < 4; ++i) {
            int row = w * 32 + mt * 16 + quad * 4 + i;
            Pp[row * 20 + l16] = pf[mt][i];
        }
    __syncthreads();
    if (tid < 128) {
        const float4* pp = (const float4*)(Pp + tid * 20);
        float4 v0 = pp[0], v1 = pp[1], v2 = pp[2], v3 = pp[3];
        float s = v0.x + v0.y + v0.z + v0.w + v1.x + v1.y + v1.z + v1.w
                + v2.x + v2.y + v2.z + v2.w + v3.x + v3.y + v3.z + v3.w;
        (hf ? fv1 : fv0)[m0 + tid] = s;     // partial (over 128 cols), pre-elu
    }
}

// ---------------- k4: elu + quadrature reduce + combine (wave per batch) ----------------
__global__ void k4_final(const float* __restrict__ x, const float* __restrict__ fv0,
                         const float* __restrict__ fv1, const float* __restrict__ ib3,
                         const float* __restrict__ cc,
                         const float* __restrict__ offs, const float* __restrict__ scal,
                         float* __restrict__ out) {
    int tid = threadIdx.x;
    int wv = tid >> 6, lane = tid & 63;
    int b = blockIdx.x * 4 + wv;
    float v = 0.f;
    if (lane < 51) {
        int m = b * 51 + lane;
        float s = fv0[m] + fv1[m] + ib3[0];
        float f = s > 0.f ? s + 1.f : __expf(s);   // elu(s)+1
        v = f * cc[lane];
    }
    #pragma unroll
    for (int mask = 1; mask < 64; mask <<= 1) v += __shfl_xor(v, mask, 64);
    if (lane == 0)
        out[b] = scal[b] * (0.5f * x[b] * v) + offs[b];
}

extern "C" void kernel_launch(void* const* d_in, const int* in_sizes, int n_in,
                              void* d_out, int out_size, void* d_ws, size_t ws_size,
                              hipStream_t stream) {
    const float* x   = (const float*)d_in[0];
    const float* h   = (const float*)d_in[1];
    const float* iw1 = (const float*)d_in[2];
    const float* ib1 = (const float*)d_in[3];
    const float* iw2 = (const float*)d_in[4];
    const float* ib2 = (const float*)d_in[5];
    const float* iw3 = (const float*)d_in[6];
    const float* ib3 = (const float*)d_in[7];
    const float* nw1 = (const float*)d_in[8];
    const float* nb1 = (const float*)d_in[9];
    const float* nw2 = (const float*)d_in[10];
    const float* nb2 = (const float*)d_in[11];
    const float* nw3 = (const float*)d_in[12];
    const float* nb3 = (const float*)d_in[13];
    float* out = (float*)d_out;

    char* ws = (char*)d_ws;
    unsigned short* iw2p = (unsigned short*)(ws + OFF_IW2P);
    float* w1xs  = (float*)(ws + OFF_W1X);
    float* cc    = (float*)(ws + OFF_CC);
    float* steps = (float*)(ws + OFF_STEPS);
    float* offs  = (float*)(ws + OFF_OFFS);
    float* scal  = (float*)(ws + OFF_SCAL);
    float* g1    = (float*)(ws + OFF_G1);
    float* fv0   = (float*)(ws + OFF_FV0);
    float* fv1   = (float*)(ws + OFF_FV1);

    k1_fused<<<dim3(769), dim3(256), 0, stream>>>(iw2, nw1, iw1, ib1, nb1, h,
                                                  nw2, nb2, nw3, nb3,
                                                  iw2p, w1xs, cc, steps, g1, offs, scal);
    k2_main<<<dim3((MTOT / 128) * 2), dim3(256), 0, stream>>>(x, g1, w1xs, iw2p, ib2, iw3,
                                                              steps, fv0, fv1);
    k4_final<<<dim3(BATCH / 4), dim3(256), 0, stream>>>(x, fv0, fv1, ib3, cc, offs, scal, out);
}

// Round 9
// 162.803 us; speedup vs baseline: 2.7196x; 1.0338x over previous
//
#include <hip/hip_runtime.h>
#include <hip/hip_bf16.h>
#include <math.h>

// Problem constants
#define BATCH 8192
#define HD    256
#define NPTS  51              // nb_steps=50 -> 51 quadrature points
#define MTOT  (BATCH*NPTS)    // 417792 = 128 * 3264

typedef __bf16 bf16x8 __attribute__((ext_vector_type(8)));
typedef float  f32x4  __attribute__((ext_vector_type(4)));

// ---- workspace layout (bytes) ----
#define OFF_IW2P  0            // 65536 ushort: iw2 bf16, CHUNK-MAJOR per col-half:
                               //   iw2p[h*32768 + c*1024 + n*8 + j] = bf16(iw2[(h*128+n)*256 + c*8 + j])
#define OFF_W1X   131072       // 256 f32 (iw1[:,0])
#define OFF_CC    132096       // 64 f32
#define OFF_STEPS 132352       // 64 f32
#define OFF_OFFS  132608       // 8192 f32
#define OFF_SCAL  165376       // 8192 f32
#define OFF_G1    198144       // 8192*256 f32 (h-part of layer1 + ib1, NO relu)
#define OFF_FV0   8586752      // 417792 f32 partial dot, col-half 0
#define OFF_FV1   10257920     // 417792 f32 partial dot, col-half 1  (ends 11929088)

__device__ __forceinline__ unsigned short f2bf(float f) {
    union { float f; unsigned u; } v; v.f = f;
    unsigned r = v.u + 0x7FFFu + ((v.u >> 16) & 1u);   // RTNE
    return (unsigned short)(r >> 16);
}

__device__ __forceinline__ unsigned pk2bf(float lo, float hi) {
    __hip_bfloat162 t = __float22bfloat162_rn(float2{lo, hi});
    union { __hip_bfloat162 b; unsigned u; } v; v.b = t;
    return v.u;
}

// ---------------- K1: fused prep + second network ----------------
__global__ void k1_fused(const float* __restrict__ iw2, const float* __restrict__ nw1,
                         const float* __restrict__ iw1, const float* __restrict__ ib1,
                         const float* __restrict__ nb1, const float* __restrict__ h,
                         const float* __restrict__ nw2, const float* __restrict__ nb2,
                         const float* __restrict__ nw3, const float* __restrict__ nb3,
                         unsigned short* iw2p, float* w1xs, float* cc, float* steps,
                         float* __restrict__ g1, float* __restrict__ offs,
                         float* __restrict__ scal) {
    int blk = blockIdx.x, tid = threadIdx.x;
    if (blk < 256) {
        int t = blk * 256 + tid;           // t = n*256 + k
        int n = t >> 8, k = t & 255;
        int half = n >> 7, nl = n & 127, c = k >> 3, j = k & 7;
        iw2p[half * 32768 + c * 1024 + nl * 8 + j] = f2bf(iw2[t]);
    } else if (blk == 256) {
        w1xs[tid] = iw1[tid * 16];   // column 0 of iw1
        const float PI_F = 3.14159265358979323846f;
        if (tid <= 50) {
            int j = tid;
            float s = 0.f;
            for (int i = 0; i <= 50; i += 2) {          // odd i have W=0
                float w = (i == 0) ? 1.f : 2.f / (1.f - (float)(i * i));
                float l;
                if (j == 0 || j == 50) l = 0.5f;
                else { int r = (i * j) % 100; l = __cosf((float)r * (PI_F / 50.f)); }
                s += l * w;
            }
            cc[j]    = s * (2.f / 50.f);
            steps[j] = __cosf((float)j * (PI_F / 50.f));
        }
    } else {
        __shared__ float hs[16][15];
        __shared__ unsigned short a1s[16][264];   // bf16 relu(h@nw1.T+nb1), padded stride
        __shared__ float Pp[4 * 2 * 16];
        int b0 = (blk - 257) * 16, n = tid;
        if (tid < 240) { int bb = tid / 15, j = tid % 15; hs[bb][j] = h[(b0 + bb) * 15 + j]; }
        __syncthreads();
        float ir[16], nr[15];
        const float4* ip = (const float4*)(iw1 + n * 16);
        ((float4*)ir)[0] = ip[0]; ((float4*)ir)[1] = ip[1];
        ((float4*)ir)[2] = ip[2]; ((float4*)ir)[3] = ip[3];
        #pragma unroll
        for (int j = 0; j < 15; ++j) nr[j] = nw1[n * 15 + j];
        float bi = ib1[n], bn = nb1[n];
        #pragma unroll
        for (int bb = 0; bb < 16; ++bb) {
            float g = bi, a = bn;
            #pragma unroll
            for (int j = 0; j < 15; ++j) { float hv = hs[bb][j]; g += hv * ir[j + 1]; a += hv * nr[j]; }
            g1[(b0 + bb) * 256 + n] = g;
            a1s[bb][n] = f2bf(fmaxf(a, 0.f));
        }
        __syncthreads();

        // ---- nnet layer2 MFMA: A = a1s (16 batches x 256k), wave w owns 64 n ----
        int lane = tid & 63, w = tid >> 6, l16 = lane & 15, quad = lane >> 4;
        f32x4 acc[4];
        #pragma unroll
        for (int nt = 0; nt < 4; ++nt) acc[nt] = (f32x4){0.f, 0.f, 0.f, 0.f};
        #pragma unroll
        for (int ks = 0; ks < 8; ++ks) {
            bf16x8 af = *(const bf16x8*)&a1s[l16][ks * 32 + quad * 8];
            #pragma unroll
            for (int nt = 0; nt < 4; ++nt) {
                const float* np = nw2 + (w * 64 + nt * 16 + l16) * 256 + ks * 32 + quad * 8;
                float4 f0 = ((const float4*)np)[0];
                float4 f1 = ((const float4*)np)[1];
                union { uint4 u; bf16x8 v; } bf;
                bf.u.x = pk2bf(f0.x, f0.y); bf.u.y = pk2bf(f0.z, f0.w);
                bf.u.z = pk2bf(f1.x, f1.y); bf.u.w = pk2bf(f1.z, f1.w);
                acc[nt] = __builtin_amdgcn_mfma_f32_16x16x32_bf16(af, bf.v, acc[nt], 0, 0, 0);
            }
        }
        float p0[4], p1[4];
        #pragma unroll
        for (int i = 0; i < 4; ++i) { p0[i] = 0.f; p1[i] = 0.f; }
        #pragma unroll
        for (int nt = 0; nt < 4; ++nt) {
            int nn = w * 64 + nt * 16 + l16;
            float bias = nb2[nn], wa = nw3[nn], wb = nw3[256 + nn];
            #pragma unroll
            for (int i = 0; i < 4; ++i) {
                float v = acc[nt][i] + bias;
                v = v > 0.f ? v : 0.f;
                p0[i] += v * wa;
                p1[i] += v * wb;
            }
        }
        #pragma unroll
        for (int mask = 1; mask < 16; mask <<= 1)
            #pragma unroll
            for (int i = 0; i < 4; ++i) {
                p0[i] += __shfl_xor(p0[i], mask, 64);
                p1[i] += __shfl_xor(p1[i], mask, 64);
            }
        if (l16 == 0) {
            #pragma unroll
            for (int i = 0; i < 4; ++i) {
                int r = quad * 4 + i;                  // 0..15
                Pp[w * 32 + r]      = p0[i];
                Pp[w * 32 + 16 + r] = p1[i];
            }
        }
        __syncthreads();
        if (tid < 16) {
            float s0 = Pp[tid]      + Pp[32 + tid] + Pp[64 + tid] + Pp[96 + tid]  + nb3[0];
            float s1 = Pp[16 + tid] + Pp[48 + tid] + Pp[80 + tid] + Pp[112 + tid] + nb3[1];
            offs[b0 + tid] = s0;
            scal[b0 + tid] = __expf(s1);
        }
    }
}

// ---------------- k2: main integrand GEMM ----------------
// Block = 128 rows x 128 cols (col-half hf), K=256. 4 waves, wave w owns rows
// [w*32, w*32+32): acc[2][8] = 64 AGPRs. R9 change: B-frag loads split into two
// groups of 4 (bfr[4] = 16 VGPRs, was 32) and both A frags computed first, so
// arch VGPRs fit the 512/4=128 unified budget -> __launch_bounds__(256,4) gives
// 4 blocks/CU (LDS 37.9KB x 4 = 151.5KB < 160KB). R7 lesson: watch WRITE_SIZE
// for spill; R8 was 140 regs @ 3 blocks/CU.
// All A-side inputs staged in LDS up front (g1 rows 4KB + w1x 1KB); K-loop
// touches global memory zero times. B streamed as four 16KB chunks, dbuf DMA.
__launch_bounds__(256, 4)
__global__ void k2_main(const float* __restrict__ x, const float* __restrict__ g1,
                        const float* __restrict__ w1xs, const unsigned short* __restrict__ iw2p,
                        const float* __restrict__ ib2, const float* __restrict__ iw3,
                        const float* __restrict__ steps,
                        float* __restrict__ fv0, float* __restrict__ fv1) {
    __shared__ __align__(16) unsigned char smem[37888];   // [0,32K) B dbuf | [32K,36K) g1 | [36K,37K) w1x
    float* Pp = (float*)smem;                             // aliased for epilogue: [128][20] f32

    int tid = threadIdx.x;
    int bid = blockIdx.x;
    int hf  = bid & 1;
    int m0  = (bid >> 1) * 128;
    int lane = tid & 63, w = tid >> 6;
    int l16 = lane & 15, quad = lane >> 4;

    unsigned blo = (unsigned)(((unsigned long long)(unsigned)m0 * 657931ull) >> 25);  // m0/51

    const unsigned char* bsrc = (const unsigned char*)iw2p + hf * 65536 + tid * 16;

    // DMA B chunk 0 into buf 0 (16KB), g1 rows blo..blo+3 (4KB), w1x (1KB)
    #pragma unroll
    for (int it = 0; it < 4; ++it)
        __builtin_amdgcn_global_load_lds(
            (const __attribute__((address_space(1))) unsigned int*)(bsrc + it * 4096),
            (__attribute__((address_space(3))) unsigned int*)(smem + tid * 16 + it * 4096),
            16, 0, 0);
    __builtin_amdgcn_global_load_lds(
        (const __attribute__((address_space(1))) unsigned int*)((const unsigned char*)(g1 + blo * 256) + tid * 16),
        (__attribute__((address_space(3))) unsigned int*)(smem + 32768 + tid * 16),
        16, 0, 0);
    if (w == 0)
        __builtin_amdgcn_global_load_lds(
            (const __attribute__((address_space(1))) unsigned int*)((const unsigned char*)w1xs + lane * 16),
            (__attribute__((address_space(3))) unsigned int*)(smem + 36864 + lane * 16),
            16, 0, 0);

    // per-m-group row constants (batch rel offset, x-scale) — overlaps with DMA
    float xs_[2]; int rel_[2];
    #pragma unroll
    for (int mt = 0; mt < 2; ++mt) {
        int m = m0 + w * 32 + mt * 16 + l16;
        unsigned b = (unsigned)(((unsigned long long)(unsigned)m * 657931ull) >> 25);  // m/51
        int p = m - (int)b * 51;
        xs_[mt] = x[b] * (steps[p] + 1.f) * 0.5f;
        rel_[mt] = (int)(b - blo) * 256;
    }

    f32x4 acc[2][8];
    #pragma unroll
    for (int mt = 0; mt < 2; ++mt)
        #pragma unroll
        for (int nt = 0; nt < 8; ++nt)
            acc[mt][nt] = (f32x4){0.f, 0.f, 0.f, 0.f};

    const float* Ag = (const float*)(smem + 32768);   // [4][256] g1 rows
    const float* Wl = (const float*)(smem + 36864);   // [256] w1x

    #pragma unroll
    for (int kc = 0; kc < 4; ++kc) {
        __syncthreads();                       // DMA(kc) drained + all waves aligned
        if (kc < 3) {                          // prefetch next chunk into other buf
            const unsigned char* s2 = bsrc + (kc + 1) * 16384;
            unsigned char* d2 = smem + ((kc + 1) & 1) * 16384 + tid * 16;
            #pragma unroll
            for (int it = 0; it < 4; ++it)
                __builtin_amdgcn_global_load_lds(
                    (const __attribute__((address_space(1))) unsigned int*)(s2 + it * 4096),
                    (__attribute__((address_space(3))) unsigned int*)(d2 + it * 4096),
                    16, 0, 0);
        }
        const unsigned short* Bl = (const unsigned short*)(smem + (kc & 1) * 16384);
        #pragma unroll
        for (int s = 0; s < 2; ++s) {
            int ks = kc * 2 + s;               // global 32-wide k-step 0..7
            int ko = ks * 32 + quad * 8;
            int cl = s * 4 + quad;             // chunk-local c 0..7

            // ---- both A fragments first (af[2] = 16 VGPRs) ----
            union { uint4 u; bf16x8 v; } af[2];
            {
                float4 w0 = ((const float4*)(Wl + ko))[0];
                float4 w1 = ((const float4*)(Wl + ko))[1];
                #pragma unroll
                for (int mt = 0; mt < 2; ++mt) {
                    const float* gp = Ag + rel_[mt] + ko;
                    float4 ga  = ((const float4*)gp)[0];
                    float4 gb2 = ((const float4*)gp)[1];
                    float xs = xs_[mt];
                    float a0 = fmaxf(ga.x  + xs * w0.x, 0.f);
                    float a1 = fmaxf(ga.y  + xs * w0.y, 0.f);
                    float a2 = fmaxf(ga.z  + xs * w0.z, 0.f);
                    float a3 = fmaxf(ga.w  + xs * w0.w, 0.f);
                    float a4 = fmaxf(gb2.x + xs * w1.x, 0.f);
                    float a5 = fmaxf(gb2.y + xs * w1.y, 0.f);
                    float a6 = fmaxf(gb2.z + xs * w1.z, 0.f);
                    float a7 = fmaxf(gb2.w + xs * w1.w, 0.f);
                    af[mt].u.x = pk2bf(a0, a1); af[mt].u.y = pk2bf(a2, a3);
                    af[mt].u.z = pk2bf(a4, a5); af[mt].u.w = pk2bf(a6, a7);
                }
            }

            // ---- B frags in two groups of 4 (bfr = 16 VGPRs live) ----
            #pragma unroll
            for (int g = 0; g < 2; ++g) {
                bf16x8 bfr[4];
                #pragma unroll
                for (int nt = 0; nt < 4; ++nt)
                    bfr[nt] = *(const bf16x8*)(Bl + (cl * 128 + (g * 4 + nt) * 16 + l16) * 8);
                #pragma unroll
                for (int mt = 0; mt < 2; ++mt)
                    #pragma unroll
                    for (int nt = 0; nt < 4; ++nt)
                        acc[mt][g * 4 + nt] = __builtin_amdgcn_mfma_f32_16x16x32_bf16(
                            af[mt].v, bfr[nt], acc[mt][g * 4 + nt], 0, 0, 0);
            }
        }
    }

    // ---- epilogue: relu(+ib2), dot with iw3 over this block's 128 cols ----
    float pf[2][4];
    #pragma unroll
    for (int mt = 0; mt < 2; ++mt)
        #pragma unroll
        for (int i = 0; i < 4; ++i) pf[mt][i] = 0.f;
    #pragma unroll
    for (int nt = 0; nt < 8; ++nt) {
        int n = hf * 128 + nt * 16 + l16;
        float bias = ib2[n], w3 = iw3[n];
        #pragma unroll
        for (int mt = 0; mt < 2; ++mt)
            #pragma unroll
            for (int i = 0; i < 4; ++i) {
                float v = acc[mt][nt][i] + bias;
                v = v > 0.f ? v : 0.f;
                pf[mt][i] += v * w3;
            }
    }
    __syncthreads();     // all Bl/Ag reads done; smem becomes Pp
    #pragma unroll
    for (int mt = 0; mt < 2; ++mt)
        #pragma unroll
        for (int i = 0; i < 4; ++i) {
            int row = w * 32 + mt * 16 + quad * 4 + i;
            Pp[row * 20 + l16] = pf[mt][i];
        }
    __syncthreads();
    if (tid < 128) {
        const float4* pp = (const float4*)(Pp + tid * 20);
        float4 v0 = pp[0], v1 = pp[1], v2 = pp[2], v3 = pp[3];
        float s = v0.x + v0.y + v0.z + v0.w + v1.x + v1.y + v1.z + v1.w
                + v2.x + v2.y + v2.z + v2.w + v3.x + v3.y + v3.z + v3.w;
        (hf ? fv1 : fv0)[m0 + tid] = s;     // partial (over 128 cols), pre-elu
    }
}

// ---------------- k4: elu + quadrature reduce + combine (wave per batch) ----------------
__global__ void k4_final(const float* __restrict__ x, const float* __restrict__ fv0,
                         const float* __restrict__ fv1, const float* __restrict__ ib3,
                         const float* __restrict__ cc,
                         const float* __restrict__ offs, const float* __restrict__ scal,
                         float* __restrict__ out) {
    int tid = threadIdx.x;
    int wv = tid >> 6, lane = tid & 63;
    int b = blockIdx.x * 4 + wv;
    float v = 0.f;
    if (lane < 51) {
        int m = b * 51 + lane;
        float s = fv0[m] + fv1[m] + ib3[0];
        float f = s > 0.f ? s + 1.f : __expf(s);   // elu(s)+1
        v = f * cc[lane];
    }
    #pragma unroll
    for (int mask = 1; mask < 64; mask <<= 1) v += __shfl_xor(v, mask, 64);
    if (lane == 0)
        out[b] = scal[b] * (0.5f * x[b] * v) + offs[b];
}

extern "C" void kernel_launch(void* const* d_in, const int* in_sizes, int n_in,
                              void* d_out, int out_size, void* d_ws, size_t ws_size,
                              hipStream_t stream) {
    const float* x   = (const float*)d_in[0];
    const float* h   = (const float*)d_in[1];
    const float* iw1 = (const float*)d_in[2];
    const float* ib1 = (const float*)d_in[3];
    const float* iw2 = (const float*)d_in[4];
    const float* ib2 = (const float*)d_in[5];
    const float* iw3 = (const float*)d_in[6];
    const float* ib3 = (const float*)d_in[7];
    const float* nw1 = (const float*)d_in[8];
    const float* nb1 = (const float*)d_in[9];
    const float* nw2 = (const float*)d_in[10];
    const float* nb2 = (const float*)d_in[11];
    const float* nw3 = (const float*)d_in[12];
    const float* nb3 = (const float*)d_in[13];
    float* out = (float*)d_out;

    char* ws = (char*)d_ws;
    unsigned short* iw2p = (unsigned short*)(ws + OFF_IW2P);
    float* w1xs  = (float*)(ws + OFF_W1X);
    float* cc    = (float*)(ws + OFF_CC);
    float* steps = (float*)(ws + OFF_STEPS);
    float* offs  = (float*)(ws + OFF_OFFS);
    float* scal  = (float*)(ws + OFF_SCAL);
    float* g1    = (float*)(ws + OFF_G1);
    float* fv0   = (float*)(ws + OFF_FV0);
    float* fv1   = (float*)(ws + OFF_FV1);

    k1_fused<<<dim3(769), dim3(256), 0, stream>>>(iw2, nw1, iw1, ib1, nb1, h,
                                                  nw2, nb2, nw3, nb3,
                                                  iw2p, w1xs, cc, steps, g1, offs, scal);
    k2_main<<<dim3((MTOT / 128) * 2), dim3(256), 0, stream>>>(x, g1, w1xs, iw2p, ib2, iw3,
                                                              steps, fv0, fv1);
    k4_final<<<dim3(BATCH / 4), dim3(256), 0, stream>>>(x, fv0, fv1, ib3, cc, offs, scal, out);
}